// Round 2
// baseline (102.472 us; speedup 1.0000x reference)
//
#include <hip/hip_runtime.h>

// Problem constants
#define Bz 4
#define Nn 1024
#define Cc 23
#define Hh 100
#define H4 25           // Hh/4
#define BT 128          // b-tile for LDS staging

// ws layout (float offsets)
#define FW_OFF   0                     // [4][25][1024] float4 = 409600 floats
#define COEF_OFF 409600                // [100] float4 = 400 floats
#define BIAS_OFF 410000                // [4]
#define CONV_OFF 410004                // [4][1024]

// ---------------------------------------------------------------------------
// prep: fw[z][h4][b] = float4 over h=4*h4+j of sum_c W2[h][c]*f[z][b][c]
//       bias[z] = sum_b sum_c b2[c]*f[z][b][c]
//       coef[h] = {W1[0][h], W1[1][h], W1[2][h], b1[h]}
// ---------------------------------------------------------------------------
__global__ void prep_kernel(const float* __restrict__ f,
                            const float* __restrict__ W1,
                            const float* __restrict__ b1,
                            const float* __restrict__ W2,
                            const float* __restrict__ b2,
                            float* __restrict__ ws) {
    int blk = blockIdx.x;
    int t = threadIdx.x;
    if (blk < 400) {
        int idx = blk * 256 + t;          // 0..102399 = 4*25*1024
        int z = idx / 25600;
        int rem = idx - z * 25600;
        int h4 = rem >> 10;
        int b = rem & 1023;
        const float* frow = f + (z * Nn + b) * Cc;
        float fr[Cc];
        #pragma unroll
        for (int c = 0; c < Cc; ++c) fr[c] = frow[c];
        float o[4];
        #pragma unroll
        for (int j = 0; j < 4; ++j) {
            const float* wrow = W2 + (h4 * 4 + j) * Cc;
            float s = 0.f;
            #pragma unroll
            for (int c = 0; c < Cc; ++c) s = fmaf(fr[c], wrow[c], s);
            o[j] = s;
        }
        reinterpret_cast<float4*>(ws + FW_OFF)[(z * H4 + h4) * Nn + b] =
            make_float4(o[0], o[1], o[2], o[3]);
    } else if (blk < 404) {
        int z = blk - 400;
        float s = 0.f;
        for (int b = t; b < Nn; b += 256) {
            const float* frow = f + (z * Nn + b) * Cc;
            #pragma unroll
            for (int c = 0; c < Cc; ++c) s = fmaf(frow[c], b2[c], s);
        }
        __shared__ float red[256];
        red[t] = s; __syncthreads();
        for (int off = 128; off; off >>= 1) {
            if (t < off) red[t] += red[t + off];
            __syncthreads();
        }
        if (t == 0) ws[BIAS_OFF + z] = red[0];
    } else {
        if (t < Hh) {
            reinterpret_cast<float4*>(ws + COEF_OFF)[t] =
                make_float4(W1[t], W1[Hh + t], W1[2 * Hh + t], b1[t]);
        }
    }
}

// ---------------------------------------------------------------------------
// main: conv[z,a] = ( sum_b sum_h relu(s·W1col + b1)_h * fw[z,b,h] + bias_z ) / 32
// Block = 512 threads = 8 waves; each wave owns one a; block covers 8 a's, all b.
// fw tile staged in LDS as [h4][bl] float4 (lane-contiguous b128 reads).
// ---------------------------------------------------------------------------
__global__ __launch_bounds__(512, 4)
void conv_kernel(const float* __restrict__ geom, float* __restrict__ ws) {
    __shared__ float4 fw_s[H4 * BT];   // 51200 B
    __shared__ float4 coef_s[Hh];      // 1600 B
    int z = blockIdx.x >> 7;
    int a0 = (blockIdx.x & 127) << 3;
    int t = threadIdx.x;
    int wave = t >> 6, lane = t & 63;
    int a = a0 + wave;

    if (t < Hh) coef_s[t] = reinterpret_cast<const float4*>(ws + COEF_OFF)[t];

    const float* ga = geom + (z * Nn + a) * 3;
    float gax = ga[0], gay = ga[1], gaz = ga[2];
    const float4* fw_g = reinterpret_cast<const float4*>(ws + FW_OFF) + z * (H4 * Nn);

    float acc = 0.f;
    for (int tile = 0; tile < Nn / BT; ++tile) {
        int b0 = tile * BT;
        __syncthreads();   // prior compute done before overwrite (also orders coef_s)
        for (int j = t; j < H4 * BT; j += 512) {
            int h4 = j >> 7, bl = j & (BT - 1);
            fw_s[j] = fw_g[h4 * Nn + b0 + bl];
        }
        __syncthreads();
        #pragma unroll
        for (int bb = 0; bb < BT; bb += 64) {
            int bl = bb + lane;
            int b = b0 + bl;
            const float* gb = geom + (z * Nn + b) * 3;
            float dx = gax - gb[0], dy = gay - gb[1], dz = gaz - gb[2];
            float r = sqrtf(fmaf(dx, dx, fmaf(dy, dy, fmaf(dz, dz, 1e-12f))));
            float u = r * (2.0f / 3.0f);
            // cos(pi*u) via v_cos_f32 (arg in revolutions)
            float cp = __builtin_amdgcn_cosf(0.5f * u);
            float p = 0.5f * (1.0f + cp);
            float m = 0.5f * (1.0f - cp);
            float s0 = (u < 1.0f) ? p : 0.0f;                 // bump @0 (u>=0 always)
            float s1 = (u < 2.0f) ? m : 0.0f;                 // bump @1.5 (0<u<2)
            float s2 = (u > 1.0f && u < 3.0f) ? p : 0.0f;     // bump @3.0 (1<u<3)
            const float4* fwp = fw_s + bl;
            #pragma unroll 5
            for (int h4 = 0; h4 < H4; ++h4) {
                float4 fv = fwp[h4 * BT];
                float4 c0 = coef_s[h4 * 4 + 0];
                float4 c1 = coef_s[h4 * 4 + 1];
                float4 c2 = coef_s[h4 * 4 + 2];
                float4 c3 = coef_s[h4 * 4 + 3];
                float h0 = fmaf(s0, c0.x, fmaf(s1, c0.y, fmaf(s2, c0.z, c0.w)));
                float h1 = fmaf(s0, c1.x, fmaf(s1, c1.y, fmaf(s2, c1.z, c1.w)));
                float h2 = fmaf(s0, c2.x, fmaf(s1, c2.y, fmaf(s2, c2.z, c2.w)));
                float h3 = fmaf(s0, c3.x, fmaf(s1, c3.y, fmaf(s2, c3.z, c3.w)));
                acc = fmaf(fmaxf(h0, 0.f), fv.x, acc);
                acc = fmaf(fmaxf(h1, 0.f), fv.y, acc);
                acc = fmaf(fmaxf(h2, 0.f), fv.z, acc);
                acc = fmaf(fmaxf(h3, 0.f), fv.w, acc);
            }
        }
    }
    #pragma unroll
    for (int off = 32; off; off >>= 1) acc += __shfl_down(acc, off);
    if (lane == 0)
        ws[CONV_OFF + z * Nn + a] = (acc + ws[BIAS_OFF + z]) * 0.03125f;
}

// ---------------------------------------------------------------------------
// head: [4,1024] -> fc1(30) relu -> fc2(10) relu -> fc3(1)
// ---------------------------------------------------------------------------
__global__ void head_kernel(const float* __restrict__ ws,
                            const float* __restrict__ Wf1, const float* __restrict__ bf1,
                            const float* __restrict__ Wf2, const float* __restrict__ bf2,
                            const float* __restrict__ Wf3, const float* __restrict__ bf3,
                            float* __restrict__ out) {
    __shared__ float x1[Bz][30];
    __shared__ float x2[Bz][10];
    int t = threadIdx.x;
    if (t < 120) {
        int z = t / 30, d = t % 30;
        const float* cz = ws + CONV_OFF + z * Nn;
        float a0 = 0, a1 = 0, a2 = 0, a3 = 0;
        for (int k = 0; k < Nn; k += 4) {
            a0 = fmaf(cz[k + 0], Wf1[(k + 0) * 30 + d], a0);
            a1 = fmaf(cz[k + 1], Wf1[(k + 1) * 30 + d], a1);
            a2 = fmaf(cz[k + 2], Wf1[(k + 2) * 30 + d], a2);
            a3 = fmaf(cz[k + 3], Wf1[(k + 3) * 30 + d], a3);
        }
        x1[z][d] = fmaxf((a0 + a1) + (a2 + a3) + bf1[d], 0.f);
    }
    __syncthreads();
    if (t < 40) {
        int z = t / 10, d = t % 10;
        float s = bf2[d];
        #pragma unroll
        for (int k = 0; k < 30; ++k) s = fmaf(x1[z][k], Wf2[k * 10 + d], s);
        x2[z][d] = fmaxf(s, 0.f);
    }
    __syncthreads();
    if (t < Bz) {
        float s = bf3[0];
        #pragma unroll
        for (int k = 0; k < 10; ++k) s = fmaf(x2[t][k], Wf3[k], s);
        out[t] = s;
    }
}

extern "C" void kernel_launch(void* const* d_in, const int* in_sizes, int n_in,
                              void* d_out, int out_size, void* d_ws, size_t ws_size,
                              hipStream_t stream) {
    const float* f   = (const float*)d_in[0];
    const float* geo = (const float*)d_in[1];
    const float* W1  = (const float*)d_in[2];
    const float* b1  = (const float*)d_in[3];
    const float* W2  = (const float*)d_in[4];
    const float* b2  = (const float*)d_in[5];
    const float* Wf1 = (const float*)d_in[6];
    const float* bf1 = (const float*)d_in[7];
    const float* Wf2 = (const float*)d_in[8];
    const float* bf2 = (const float*)d_in[9];
    const float* Wf3 = (const float*)d_in[10];
    const float* bf3 = (const float*)d_in[11];
    float* ws  = (float*)d_ws;
    float* out = (float*)d_out;

    hipLaunchKernelGGL(prep_kernel, dim3(405), dim3(256), 0, stream, f, W1, b1, W2, b2, ws);
    hipLaunchKernelGGL(conv_kernel, dim3(512), dim3(512), 0, stream, geo, ws);
    hipLaunchKernelGGL(head_kernel, dim3(1), dim3(128), 0, stream,
                       ws, Wf1, bf1, Wf2, bf2, Wf3, bf3, out);
}